// Round 1
// 399.080 us; speedup vs baseline: 1.0468x; 1.0468x over previous
//
#include <hip/hip_runtime.h>
#include <hip/hip_bf16.h>

#define N_NODES 50000
#define N_EDGES 800000
#define HIDDEN  256
#define N_LAYERS 3
#define N_PAIRS 4096
#define N_LABEL 8192            // 2*N_PAIRS labeled rows
#define NPAD    50176           // 196*256, padded node count for the scan
#define SCAN_BLOCKS (NPAD / 256) // 196
#define WSZ (HIDDEN * HIDDEN)    // 65536 elems per weight matrix

// Column-blocked x0 layout for the XCD-sliced segment sum:
//   x0b[slice][node][32], slice = col>>5. One slice = 3.2 MB < 4 MB XCD L2.
#define SLICE_ELEMS ((size_t)N_NODES * 32)
#define SEG_CHUNKS ((N_NODES + 63) / 64)   // 782

typedef __bf16 bf16x8 __attribute__((ext_vector_type(8)));
typedef __bf16 bf16x4 __attribute__((ext_vector_type(4)));
typedef float  f32x4  __attribute__((ext_vector_type(4)));

__device__ __forceinline__ void load_lds16(const void* g, void* l) {
    __builtin_amdgcn_global_load_lds(
        (const __attribute__((address_space(1))) void*)g,
        (__attribute__((address_space(3))) void*)l, 16, 0, 0);
}

// ---------------------------------------------------------------------------
// FUSED layer GEMM (R13): one launch does BOTH node linears of a layer.
//   blockIdx.z==0 : x0[r] = A[r]@Wt0^T (+deg*bD0) + bC0 for all r, but
//                   stores SUPPRESSED on labeled rows (flags[r]!=0)
//   blockIdx.z==1 : x0[idx[r]] = A[idx[r]]@Wt1^T (+deg*bD1) + bC1
//                   (only blockIdx.x < N_LABEL/64 active)
// Writes are disjoint by construction -> race-free in a single launch.
// R14: Cout is written in COLUMN-BLOCKED layout x0b[col>>5][row][col&31]
//      so the sliced seg-sum gathers hit contiguous 64B rows per slice.
// 64x128 tile, BK=32, 4 waves stacked in m, 1x8 frags/wave.
// ---------------------------------------------------------------------------
template <bool DEG_BIAS, bool A_FP32>
__global__ __launch_bounds__(256) void mfma_gemm_fused(
    const void* __restrict__ A_in,
    const __bf16* __restrict__ Wt0, const __bf16* __restrict__ Wt1,
    const float* __restrict__ bD0, const float* __restrict__ bD1,
    const float* __restrict__ bC0, const float* __restrict__ bC1,
    __bf16* __restrict__ Cout,
    const int* __restrict__ idx,     // pos (labeled rows)
    const int* __restrict__ offs,
    const int* __restrict__ flags,   // 1 = labeled row
    int M)
{
    const int role = blockIdx.z;
    if (role == 1 && blockIdx.x >= N_LABEL / 64) return;

    const __bf16* A   = (const __bf16*)A_in;
    const float*  A32 = (const float*)A_in;
    const __bf16* Wt  = role ? Wt1 : Wt0;
    const float*  bD  = role ? bD1 : bD0;
    const float*  bC  = role ? bC1 : bC0;

    __shared__ __bf16 As[64 * 32];    // 4 KB
    __shared__ __bf16 Bs[128 * 32];   // 8 KB
    __shared__ int s_idx[64];

    const int t    = threadIdx.x;
    const int lane = t & 63;
    const int wave = t >> 6;
    const int m0   = blockIdx.x * 64;
    const int n0   = blockIdx.y * 128;

    if (role == 1) {
        if (t < 64) s_idx[t] = idx[m0 + t];
        __syncthreads();
    }

    // A staging: chunk t; row=t>>2, col8=(t&3)*8. B: chunks r*256+t.
    // LDS dest = chunk*16 B (wave-uniform base + lane*16: m104-safe)
    const int arow  = t >> 2;
    const int acol8 = (t & 3) * 8;
    int anode;
    if (role == 1) {
        anode = s_idx[arow];
    } else {
        const int rg = m0 + arow;
        anode = (rg < M) ? rg : (M - 1);   // clamp; stores guarded below
    }
    const __bf16* aptr   = A   + (size_t)anode * HIDDEN + acol8;
    const float*  aptr32 = A32 + (size_t)anode * HIDDEN + acol8;

    const __bf16* bptr[2];
    #pragma unroll
    for (int r = 0; r < 2; ++r) {
        const int c = r * 256 + t;
        bptr[r] = Wt + (size_t)(n0 + (c >> 2)) * HIDDEN + (c & 3) * 8;
    }

    f32x4 acc[8];
    #pragma unroll
    for (int i = 0; i < 8; ++i) acc[i] = (f32x4){0.f, 0.f, 0.f, 0.f};

    const int wm   = wave * 16;
    const int fm   = lane & 15;
    const int quad = lane >> 4;

    for (int k0 = 0; k0 < HIDDEN; k0 += 32) {
        __syncthreads();
        if constexpr (A_FP32) {
            const float* ap = aptr32 + k0;
            const float4 u0 = *(const float4*)(ap);
            const float4 u1 = *(const float4*)(ap + 4);
            bf16x8 w = {(__bf16)u0.x, (__bf16)u0.y, (__bf16)u0.z, (__bf16)u0.w,
                        (__bf16)u1.x, (__bf16)u1.y, (__bf16)u1.z, (__bf16)u1.w};
            *(bf16x8*)(As + (size_t)t * 8) = w;
        } else {
            load_lds16(aptr + k0, (void*)(As + (size_t)t * 8));
        }
        #pragma unroll
        for (int r = 0; r < 2; ++r)
            load_lds16(bptr[r] + k0, (void*)(Bs + (size_t)(r * 256 + t) * 8));
        __syncthreads();

        const bf16x8 af = *(const bf16x8*)(As + (wm + fm) * 32 + quad * 8);
        bf16x8 bfr[8];
        #pragma unroll
        for (int nt = 0; nt < 8; ++nt)
            bfr[nt] = *(const bf16x8*)(Bs + (nt * 16 + fm) * 32 + quad * 8);

        #pragma unroll
        for (int nt = 0; nt < 8; ++nt)
            acc[nt] = __builtin_amdgcn_mfma_f32_16x16x32_bf16(
                af, bfr[nt], acc[nt], 0, 0, 0);
    }

    // epilogue: C/D layout col=lane&15, row=quad*4+reg (m89/m91-verified)
    float bd[8], bc[8];
    #pragma unroll
    for (int nt = 0; nt < 8; ++nt) {
        const int col = n0 + nt * 16 + fm;
        bd[nt] = DEG_BIAS ? bD[col] : 0.f;
        bc[nt] = bC[col];
    }

    #pragma unroll
    for (int rg = 0; rg < 4; ++rg) {
        const int rloc = wm + quad * 4 + rg;
        int orow;
        if (role == 1) {
            orow = s_idx[rloc];
        } else {
            orow = m0 + rloc;
            if (orow >= M) continue;
            if (flags[orow]) continue;     // labeled: z=1 writes this row
        }
        float bscale = 0.f;
        if constexpr (DEG_BIAS)
            bscale = (float)(offs[orow + 1] - offs[orow]);
        #pragma unroll
        for (int nt = 0; nt < 8; ++nt) {
            const int cb = n0 + nt * 16;       // 16-col group, no 32-boundary cross
            float v = acc[nt][rg];
            if constexpr (DEG_BIAS) v += bscale * bd[nt];
            v += bc[nt];
            // column-blocked store: x0b[cb>>5][orow][ (cb&31)+fm ]
            Cout[(size_t)(cb >> 5) * SLICE_ELEMS + (size_t)orow * 32
                 + (cb & 31) + fm] = (__bf16)v;
        }
    }
}

// ---------------------------------------------------------------------------
// Plain MFMA GEMM (product batch + final out GEMM).  64x128 tile.
//   GATHER_A   : A-rows gathered via idx (A indexed by node id)
//   DEG_VIA_IDX: A sequential/compact but deg looked up via idx[rloc]
// Row-major in/out (NOT blocked) — only the fused GEMM feeds the seg-sum.
// ---------------------------------------------------------------------------
template <bool GATHER_A, bool DEG_BIAS, bool DEG_VIA_IDX, bool OUT_BF16, bool PROD_BATCH>
__global__ __launch_bounds__(256) void mfma_gemm(
    const __bf16* __restrict__ A_in,
    const __bf16* __restrict__ Wt_in,
    const float* __restrict__ biasD,
    void* __restrict__ Cout_in,
    const int* __restrict__ idx,
    const int* __restrict__ offs,
    int M)
{
    const __bf16* A  = A_in;
    const __bf16* Wt = Wt_in;
    void* Cout = Cout_in;
    if constexpr (PROD_BATCH) {
        const int z = blockIdx.z;
        A    = A_in  + (size_t)(3 * (1 + (z >> 1)) + (z & 1)) * WSZ;
        Wt   = Wt_in + (size_t)(z >> 1) * WSZ;
        Cout = (void*)((__bf16*)Cout_in + (size_t)z * WSZ);
    }

    __shared__ __bf16 As[64 * 32];
    __shared__ __bf16 Bs[128 * 32];
    __shared__ int s_idx[64];

    const int t    = threadIdx.x;
    const int lane = t & 63;
    const int wave = t >> 6;
    const int m0   = blockIdx.x * 64;
    const int n0   = blockIdx.y * 128;

    if constexpr (GATHER_A || DEG_VIA_IDX) {
        if (t < 64) s_idx[t] = idx[m0 + t];
        __syncthreads();
    }

    const int arow  = t >> 2;
    const int acol8 = (t & 3) * 8;
    int anode;
    if constexpr (GATHER_A) {
        anode = s_idx[arow];
    } else {
        const int rg = m0 + arow;
        anode = (rg < M) ? rg : (M - 1);
    }
    const __bf16* aptr = A + (size_t)anode * HIDDEN + acol8;

    const __bf16* bptr[2];
    #pragma unroll
    for (int r = 0; r < 2; ++r) {
        const int c = r * 256 + t;
        bptr[r] = Wt + (size_t)(n0 + (c >> 2)) * HIDDEN + (c & 3) * 8;
    }

    f32x4 acc[8];
    #pragma unroll
    for (int i = 0; i < 8; ++i) acc[i] = (f32x4){0.f, 0.f, 0.f, 0.f};

    const int wm   = wave * 16;
    const int fm   = lane & 15;
    const int quad = lane >> 4;

    for (int k0 = 0; k0 < HIDDEN; k0 += 32) {
        __syncthreads();
        load_lds16(aptr + k0, (void*)(As + (size_t)t * 8));
        #pragma unroll
        for (int r = 0; r < 2; ++r)
            load_lds16(bptr[r] + k0, (void*)(Bs + (size_t)(r * 256 + t) * 8));
        __syncthreads();

        const bf16x8 af = *(const bf16x8*)(As + (wm + fm) * 32 + quad * 8);
        bf16x8 bfr[8];
        #pragma unroll
        for (int nt = 0; nt < 8; ++nt)
            bfr[nt] = *(const bf16x8*)(Bs + (nt * 16 + fm) * 32 + quad * 8);

        #pragma unroll
        for (int nt = 0; nt < 8; ++nt)
            acc[nt] = __builtin_amdgcn_mfma_f32_16x16x32_bf16(
                af, bfr[nt], acc[nt], 0, 0, 0);
    }

    float bd[8];
    #pragma unroll
    for (int nt = 0; nt < 8; ++nt)
        bd[nt] = DEG_BIAS ? biasD[n0 + nt * 16 + fm] : 0.f;

    #pragma unroll
    for (int rg = 0; rg < 4; ++rg) {
        const int rloc = wm + quad * 4 + rg;
        const int orow = m0 + rloc;
        if (!PROD_BATCH && orow >= M) continue;
        int dnode = orow;
        if constexpr (GATHER_A || DEG_VIA_IDX) dnode = s_idx[rloc];
        float bscale = 0.f;
        if constexpr (DEG_BIAS)
            bscale = (float)(offs[dnode + 1] - offs[dnode]);
        #pragma unroll
        for (int nt = 0; nt < 8; ++nt) {
            const int col = n0 + nt * 16 + fm;
            float v = acc[nt][rg];
            if constexpr (DEG_BIAS) v += bscale * bd[nt];
            if constexpr (OUT_BF16)
                ((__bf16*)Cout)[(size_t)orow * HIDDEN + col] = (__bf16)v;
            else
                ((float*)Cout)[(size_t)orow * HIDDEN + col] = v;
        }
    }
}

// ---------------------------------------------------------------------------
// Weight prep, 12 z-slices in ONE launch:
//  z 0..8 : T[z][n][k] = (bf16)W_z[k][n]   (transpose; z = layer*3 + which)
//  z 9..10: cw_nt[z-9] = (bf16)conv_w[z-9] (straight convert)
//  z 11   : qprod — blocks (x<4, y==0): q[x][n] = sum_k cb_l[k]*W[k][n]
// ---------------------------------------------------------------------------
__global__ __launch_bounds__(256) void wconv_kernel(
    const float* __restrict__ f0_w, const float* __restrict__ f1_w,
    const float* __restrict__ conv_w, const float* __restrict__ conv_b,
    __bf16* __restrict__ wt_all, __bf16* __restrict__ cw_nt,
    float* __restrict__ q)
{
    const int z = blockIdx.z;
    const int kx = blockIdx.x * 32, nx = blockIdx.y * 32;
    const int tx = threadIdx.x, ty = threadIdx.y;

    if (z < 9) {
        const int layer = z / 3, which = z % 3;
        const float* W = ((which == 0) ? f0_w : (which == 1) ? f1_w : conv_w)
                         + (size_t)layer * WSZ;
        __bf16* T = wt_all + (size_t)z * WSZ;

        __shared__ float tile[32][33];
        for (int i = ty; i < 32; i += 8)
            tile[i][tx] = W[(size_t)(kx + i) * HIDDEN + nx + tx];
        __syncthreads();
        for (int i = ty; i < 32; i += 8)
            T[(size_t)(nx + i) * HIDDEN + kx + tx] = (__bf16)tile[tx][i];
    } else if (z < 11) {
        const int layer = z - 9;
        const float* W = conv_w + (size_t)layer * WSZ;
        __bf16* T = cw_nt + (size_t)layer * WSZ;
        for (int i = ty; i < 32; i += 8)
            T[(size_t)(kx + i) * HIDDEN + nx + tx] =
                (__bf16)W[(size_t)(kx + i) * HIDDEN + nx + tx];
    } else {
        // qprod: 4 active blocks (x<4, y==0), 256 threads each
        if (blockIdx.x >= 4 || blockIdx.y != 0) return;
        const int zq = blockIdx.x;
        const int l = zq >> 1, branch = zq & 1;
        const float* cb = conv_b + (size_t)l * HIDDEN;
        const float* W  = (branch ? f1_w : f0_w) + (size_t)(l + 1) * WSZ;
        const int n = ty * 32 + tx;
        float s = 0.f;
        #pragma unroll 4
        for (int k = 0; k < HIDDEN; ++k)
            s += cb[k] * W[(size_t)k * HIDDEN + n];
        q[(size_t)zq * HIDDEN + n] = s;
    }
}

// ---------------------------------------------------------------------------
// CSR build: histogram (+labeled-row flags) -> 2-level scan -> fill
// ---------------------------------------------------------------------------
__global__ __launch_bounds__(256) void hist_kernel(
    const int* __restrict__ dst, const int* __restrict__ pos,
    int* __restrict__ counts, int* __restrict__ flags)
{
    int e = blockIdx.x * 256 + threadIdx.x;
    if (e < N_EDGES) atomicAdd(&counts[dst[e]], 1);
    if (e < N_LABEL) flags[pos[e]] = 1;   // benign dup writes
}

__device__ __forceinline__ int block_incl_scan(int v, int* s, int t)
{
    s[t] = v; __syncthreads();
    #pragma unroll
    for (int off = 1; off < 256; off <<= 1) {
        int add = (t >= off) ? s[t - off] : 0;
        __syncthreads();
        s[t] += add;
        __syncthreads();
    }
    return s[t];
}

__global__ __launch_bounds__(256) void scan1_kernel(
    const int* __restrict__ counts, int* __restrict__ offs, int* __restrict__ bsum)
{
    __shared__ int s[256];
    const int t = threadIdx.x;
    const int i = blockIdx.x * 256 + t;
    const int v = counts[i];
    int incl = block_incl_scan(v, s, t);
    offs[i] = incl - v;
    if (t == 255) bsum[blockIdx.x] = incl;
}

__global__ __launch_bounds__(256) void scan2_kernel(
    const int* __restrict__ bsum, int* __restrict__ bbase)
{
    __shared__ int s[256];
    const int t = threadIdx.x;
    const int v = (t < SCAN_BLOCKS) ? bsum[t] : 0;
    int incl = block_incl_scan(v, s, t);
    bbase[t] = incl - v;
}

__global__ __launch_bounds__(256) void scan3_kernel(
    int* __restrict__ offs, const int* __restrict__ bbase, int* __restrict__ cursor)
{
    const int i = blockIdx.x * 256 + threadIdx.x;
    const int o = offs[i] + bbase[blockIdx.x];
    offs[i] = o;
    cursor[i] = o;
}

__global__ __launch_bounds__(256) void fill_kernel(
    const int* __restrict__ src, const int* __restrict__ dst,
    int* __restrict__ cursor, int* __restrict__ src_sorted)
{
    int e = blockIdx.x * 256 + threadIdx.x;
    if (e < N_EDGES) {
        int p = atomicAdd(&cursor[dst[e]], 1);
        src_sorted[p] = src[e];
    }
}

// ---------------------------------------------------------------------------
// XCD-sliced pull-mode segment sum (R14).
// x0b is column-blocked [8][N_NODES][32]; slice = blockIdx.x & 7 which, by the
// round-robin workgroup dispatch (m09/m157), pins each column slice to one
// XCD. Per-XCD gather working set = 3.2 MB < 4 MB L2 -> L2-resident gathers
// (old structure forced 6.8x full-25.6MB per-XCD L2 fills, FETCH 173 MB).
// 4-lane groups (8 cols/lane), 16 groups/wave, 64 dst rows/block.
// Output is row-major (feeds the next GEMM's A-path unchanged).
// ---------------------------------------------------------------------------
template <bool COMPACT>
__global__ __launch_bounds__(256) void seg_slice_kernel(
    const __bf16* __restrict__ x0b,
    const int* __restrict__ srcs,
    const int* __restrict__ offs,
    const int* __restrict__ nodelist,
    __bf16* __restrict__ out)
{
    const int slice = blockIdx.x & 7;
    const int chunk = blockIdx.x >> 3;
    const int t    = threadIdx.x;
    const int wave = t >> 6;
    const int lane = t & 63;
    const int g    = lane >> 2;      // 16 groups per wave
    const int li   = lane & 3;       // 4 lanes per dst row, 8 cols each
    const int rw   = chunk * 64 + wave * 16 + g;
    if (!COMPACT && rw >= N_NODES) return;

    const int d   = COMPACT ? nodelist[rw] : rw;
    const int beg = offs[d];
    const int deg = offs[d + 1] - beg;

    const __bf16* xs = x0b + (size_t)slice * SLICE_ELEMS + li * 8;

    float a[8];
    #pragma unroll
    for (int q = 0; q < 8; ++q) a[q] = 0.f;

    // window-4 src stream with next-window index prefetch
    int vs = (li < deg) ? srcs[beg + li] : 0;
    for (int base = 0; base < deg; base += 4) {
        const int rem = deg - base;
        const int n   = rem < 4 ? rem : 4;
        const int nb  = base + 4;
        int vs_n = 0;
        if (nb + li < deg) vs_n = srcs[beg + nb + li];

        int ss[4];
        #pragma unroll
        for (int k = 0; k < 4; ++k) ss[k] = __shfl(vs, (g << 2) + k);
        bf16x8 c[4];
        #pragma unroll
        for (int k = 0; k < 4; ++k)
            if (k < n) c[k] = *(const bf16x8*)(xs + (size_t)ss[k] * 32);
        #pragma unroll
        for (int k = 0; k < 4; ++k) {
            if (k < n) {
                #pragma unroll
                for (int q = 0; q < 8; ++q) a[q] += (float)c[k][q];
            }
        }
        vs = vs_n;
    }

    bf16x8 o;
    #pragma unroll
    for (int q = 0; q < 8; ++q) o[q] = (__bf16)a[q];
    *(bf16x8*)(out + (size_t)rw * HIDDEN + (slice << 5) + li * 8) = o;
}

extern "C" void kernel_launch(void* const* d_in, const int* in_sizes, int n_in,
                              void* d_out, int out_size, void* d_ws, size_t ws_size,
                              hipStream_t stream)
{
    const float* x       = (const float*)d_in[0];
    const float* f0_w    = (const float*)d_in[1];
    const float* f0_b    = (const float*)d_in[2];
    const float* f1_w    = (const float*)d_in[3];
    const float* f1_b    = (const float*)d_in[4];
    const float* conv_w  = (const float*)d_in[5];
    const float* conv_b  = (const float*)d_in[6];
    const int*   edge_src = (const int*)d_in[7];
    const int*   edge_dst = (const int*)d_in[8];
    const int*   pos      = (const int*)d_in[9];
    float* out = (float*)d_out;

    const size_t buf = (size_t)N_NODES * HIDDEN;   // 12.8M elems

    char* p = (char*)d_ws;
    __bf16* bufA   = (__bf16*)p; p += buf * 2;      // 25.6 MB (row-major S)
    __bf16* bufB   = (__bf16*)p; p += buf * 2;      // 25.6 MB (blocked x0)
    __bf16* s_lbl  = (__bf16*)p; p += (size_t)N_LABEL * HIDDEN * 2;  // 4 MB
    __bf16* wt_all = (__bf16*)p; p += (size_t)9 * WSZ * 2;
    __bf16* prod   = (__bf16*)p; p += (size_t)4 * WSZ * 2;
    __bf16* cw_nt  = (__bf16*)p; p += (size_t)2 * WSZ * 2;
    float*  qv     = (float*)p;  p += (size_t)4 * HIDDEN * 4;
    int* counts     = (int*)p;  p += NPAD * 4;     // reused as cursor
    int* flags      = (int*)p;  p += NPAD * 4;     // labeled-row bitmap
    int* offs       = (int*)p;  p += NPAD * 4;
    int* bsum       = (int*)p;  p += 256 * 4;
    int* bbase      = (int*)p;  p += 256 * 4;
    int* src_sorted = (int*)p;  p += (size_t)N_EDGES * 4;
    int* cursor = counts;       // counts dead after scan1

    const int edge_blocks = (N_EDGES + 255) / 256;   // 3125

    // ---- CSR build + flags (one memset covers counts+flags) ----
    hipMemsetAsync(counts, 0, 2 * NPAD * sizeof(int), stream);
    hist_kernel<<<edge_blocks, 256, 0, stream>>>(edge_dst, pos, counts, flags);
    scan1_kernel<<<SCAN_BLOCKS, 256, 0, stream>>>(counts, offs, bsum);
    scan2_kernel<<<1, 256, 0, stream>>>(bsum, bbase);
    scan3_kernel<<<SCAN_BLOCKS, 256, 0, stream>>>(offs, bbase, cursor);
    fill_kernel<<<edge_blocks, 256, 0, stream>>>(edge_src, edge_dst, cursor, src_sorted);

    // ---- weight prep: transpose (9) + straight Cw (2) + qprod, one launch ----
    wconv_kernel<<<dim3(8, 8, 12), dim3(32, 8), 0, stream>>>(
        f0_w, f1_w, conv_w, conv_b, wt_all, cw_nt, qv);

    // all 4 products prod_t[z] = (Cw_l · F_{l+1})^T in ONE batched launch
    mfma_gemm<false, false, false, true, true><<<dim3(4, 2, 4), 256, 0, stream>>>(
        wt_all, cw_nt, nullptr, prod, nullptr, nullptr, HIDDEN);

    const dim3 fused_grid(782, 2, 2);   // z=0 full (store-suppressed), z=1 label
    const dim3 lbl_grid(128, 2);

    __bf16* cur = bufA;              // S buffer (layer-0 GEMMs read x fp32)
    __bf16* tmp = bufB;              // x0 buffer, COLUMN-BLOCKED layout

    for (int l = 0; l < N_LAYERS; ++l) {
        const float* B0 = f0_b + (size_t)l * HIDDEN;
        const float* B1 = f1_b + (size_t)l * HIDDEN;

        if (l == 0) {
            // x0 = x@F0_0+b0 (all, minus labeled) ∪ x@F1_0+b1 (labeled)
            mfma_gemm_fused<false, true><<<fused_grid, 256, 0, stream>>>(
                x, wt_all + 0 * WSZ, wt_all + 1 * WSZ,
                nullptr, nullptr, B0, B1, tmp, pos, offs, flags, N_NODES);
        } else {
            // x0 = S@(Cw·F0_l)+deg*q0+b0 ∪ S@(Cw·F1_l)+deg*q1+b1 (folded conv)
            const int z0 = (l - 1) * 2;
            mfma_gemm_fused<true, false><<<fused_grid, 256, 0, stream>>>(
                cur, prod + (size_t)z0 * WSZ, prod + (size_t)(z0 + 1) * WSZ,
                qv + (size_t)z0 * HIDDEN, qv + (size_t)(z0 + 1) * HIDDEN,
                B0, B1, tmp, pos, offs, flags, N_NODES);
        }

        if (l < N_LAYERS - 1) {
            // S = segment_sum(x0[src]) at ALL nodes (tmp -> cur), XCD-sliced
            seg_slice_kernel<false><<<8 * SEG_CHUNKS, 256, 0, stream>>>(
                tmp, src_sorted, offs, nullptr, cur);
        } else {
            // S only at labeled dst nodes (tmp -> s_lbl, compact pos order)
            seg_slice_kernel<true><<<8 * (N_LABEL / 64), 256, 0, stream>>>(
                tmp, src_sorted, offs, pos, s_lbl);
            // out[i] = S_lbl[i] @ Cw_2 + deg[pos[i]]*cb_2  -> d_out (fp32)
            mfma_gemm<false, true, true, false, false><<<lbl_grid, 256, 0, stream>>>(
                s_lbl, wt_all + (size_t)(2 * 3 + 2) * WSZ,
                conv_b + (size_t)2 * HIDDEN, out, pos, offs, N_LABEL);
        }
    }
}

// Round 2
// 389.507 us; speedup vs baseline: 1.0725x; 1.0246x over previous
//
#include <hip/hip_runtime.h>
#include <hip/hip_bf16.h>

#define N_NODES 50000
#define N_EDGES 800000
#define HIDDEN  256
#define N_LAYERS 3
#define N_PAIRS 4096
#define N_LABEL 8192            // 2*N_PAIRS labeled rows
#define NPAD    50176           // 196*256, padded node count for the scan
#define SCAN_BLOCKS (NPAD / 256) // 196
#define WSZ (HIDDEN * HIDDEN)    // 65536 elems per weight matrix

// Column-blocked x0 layout for the XCD-sliced segment sum:
//   x0b[slice][node][32], slice = col>>5. One slice = 3.2 MB < 4 MB XCD L2.
// Row N_NODES is an all-zero SENTINEL row: CSR segments are padded to a
// multiple of 8 with edges pointing at it -> branch-free window-8 seg loop.
#define NROWPAD (N_NODES + 1)
#define SLICE_ELEMS ((size_t)NROWPAD * 32)
#define SEG_CHUNKS ((N_NODES + 63) / 64)   // 782

typedef __bf16 bf16x8 __attribute__((ext_vector_type(8)));
typedef __bf16 bf16x4 __attribute__((ext_vector_type(4)));
typedef float  f32x4  __attribute__((ext_vector_type(4)));
typedef float  f32x2  __attribute__((ext_vector_type(2)));

__device__ __forceinline__ void load_lds16(const void* g, void* l) {
    __builtin_amdgcn_global_load_lds(
        (const __attribute__((address_space(1))) void*)g,
        (__attribute__((address_space(3))) void*)l, 16, 0, 0);
}

// accumulate 8 bf16 (as uint4) into 4 packed f32 pairs: 3 VALU per pair
// (shl, and, v_pk_add_f32) instead of 4 (cvt+add x2).
__device__ __forceinline__ void acc8(const uint4 w, f32x2* a) {
    a[0] += (f32x2){__uint_as_float(w.x << 16), __uint_as_float(w.x & 0xffff0000u)};
    a[1] += (f32x2){__uint_as_float(w.y << 16), __uint_as_float(w.y & 0xffff0000u)};
    a[2] += (f32x2){__uint_as_float(w.z << 16), __uint_as_float(w.z & 0xffff0000u)};
    a[3] += (f32x2){__uint_as_float(w.w << 16), __uint_as_float(w.w & 0xffff0000u)};
}

// ---------------------------------------------------------------------------
// FUSED layer GEMM (R13): one launch does BOTH node linears of a layer.
//   blockIdx.z==0 : x0[r] = A[r]@Wt0^T (+deg*bD0) + bC0 for all r, but
//                   stores SUPPRESSED on labeled rows (flags[r]!=0)
//   blockIdx.z==1 : x0[idx[r]] = A[idx[r]]@Wt1^T (+deg*bD1) + bC1
// Writes are disjoint by construction -> race-free in a single launch.
// Cout written COLUMN-BLOCKED x0b[col>>5][row][col&31] for the sliced seg.
// R15: deg now comes from degv[] (true counts) since offs[] is PADDED.
// ---------------------------------------------------------------------------
template <bool DEG_BIAS, bool A_FP32>
__global__ __launch_bounds__(256) void mfma_gemm_fused(
    const void* __restrict__ A_in,
    const __bf16* __restrict__ Wt0, const __bf16* __restrict__ Wt1,
    const float* __restrict__ bD0, const float* __restrict__ bD1,
    const float* __restrict__ bC0, const float* __restrict__ bC1,
    __bf16* __restrict__ Cout,
    const int* __restrict__ idx,     // pos (labeled rows)
    const int* __restrict__ degv,    // true degree per node
    const int* __restrict__ flags,   // 1 = labeled row
    int M)
{
    const int role = blockIdx.z;
    if (role == 1 && blockIdx.x >= N_LABEL / 64) return;

    const __bf16* A   = (const __bf16*)A_in;
    const float*  A32 = (const float*)A_in;
    const __bf16* Wt  = role ? Wt1 : Wt0;
    const float*  bD  = role ? bD1 : bD0;
    const float*  bC  = role ? bC1 : bC0;

    __shared__ __bf16 As[64 * 32];    // 4 KB
    __shared__ __bf16 Bs[128 * 32];   // 8 KB
    __shared__ int s_idx[64];

    const int t    = threadIdx.x;
    const int lane = t & 63;
    const int wave = t >> 6;
    const int m0   = blockIdx.x * 64;
    const int n0   = blockIdx.y * 128;

    if (role == 1) {
        if (t < 64) s_idx[t] = idx[m0 + t];
        __syncthreads();
    }

    const int arow  = t >> 2;
    const int acol8 = (t & 3) * 8;
    int anode;
    if (role == 1) {
        anode = s_idx[arow];
    } else {
        const int rg = m0 + arow;
        anode = (rg < M) ? rg : (M - 1);   // clamp; stores guarded below
    }
    const __bf16* aptr   = A   + (size_t)anode * HIDDEN + acol8;
    const float*  aptr32 = A32 + (size_t)anode * HIDDEN + acol8;

    const __bf16* bptr[2];
    #pragma unroll
    for (int r = 0; r < 2; ++r) {
        const int c = r * 256 + t;
        bptr[r] = Wt + (size_t)(n0 + (c >> 2)) * HIDDEN + (c & 3) * 8;
    }

    f32x4 acc[8];
    #pragma unroll
    for (int i = 0; i < 8; ++i) acc[i] = (f32x4){0.f, 0.f, 0.f, 0.f};

    const int wm   = wave * 16;
    const int fm   = lane & 15;
    const int quad = lane >> 4;

    for (int k0 = 0; k0 < HIDDEN; k0 += 32) {
        __syncthreads();
        if constexpr (A_FP32) {
            const float* ap = aptr32 + k0;
            const float4 u0 = *(const float4*)(ap);
            const float4 u1 = *(const float4*)(ap + 4);
            bf16x8 w = {(__bf16)u0.x, (__bf16)u0.y, (__bf16)u0.z, (__bf16)u0.w,
                        (__bf16)u1.x, (__bf16)u1.y, (__bf16)u1.z, (__bf16)u1.w};
            *(bf16x8*)(As + (size_t)t * 8) = w;
        } else {
            load_lds16(aptr + k0, (void*)(As + (size_t)t * 8));
        }
        #pragma unroll
        for (int r = 0; r < 2; ++r)
            load_lds16(bptr[r] + k0, (void*)(Bs + (size_t)(r * 256 + t) * 8));
        __syncthreads();

        const bf16x8 af = *(const bf16x8*)(As + (wm + fm) * 32 + quad * 8);
        bf16x8 bfr[8];
        #pragma unroll
        for (int nt = 0; nt < 8; ++nt)
            bfr[nt] = *(const bf16x8*)(Bs + (nt * 16 + fm) * 32 + quad * 8);

        #pragma unroll
        for (int nt = 0; nt < 8; ++nt)
            acc[nt] = __builtin_amdgcn_mfma_f32_16x16x32_bf16(
                af, bfr[nt], acc[nt], 0, 0, 0);
    }

    // epilogue: C/D layout col=lane&15, row=quad*4+reg (m89/m91-verified)
    float bd[8], bc[8];
    #pragma unroll
    for (int nt = 0; nt < 8; ++nt) {
        const int col = n0 + nt * 16 + fm;
        bd[nt] = DEG_BIAS ? bD[col] : 0.f;
        bc[nt] = bC[col];
    }

    #pragma unroll
    for (int rg = 0; rg < 4; ++rg) {
        const int rloc = wm + quad * 4 + rg;
        int orow;
        if (role == 1) {
            orow = s_idx[rloc];
        } else {
            orow = m0 + rloc;
            if (orow >= M) continue;
            if (flags[orow]) continue;     // labeled: z=1 writes this row
        }
        float bscale = 0.f;
        if constexpr (DEG_BIAS)
            bscale = (float)degv[orow];
        #pragma unroll
        for (int nt = 0; nt < 8; ++nt) {
            const int cb = n0 + nt * 16;       // 16-col group, no 32-boundary cross
            float v = acc[nt][rg];
            if constexpr (DEG_BIAS) v += bscale * bd[nt];
            v += bc[nt];
            // column-blocked store: x0b[cb>>5][orow][ (cb&31)+fm ]
            Cout[(size_t)(cb >> 5) * SLICE_ELEMS + (size_t)orow * 32
                 + (cb & 31) + fm] = (__bf16)v;
        }
    }
}

// ---------------------------------------------------------------------------
// Plain MFMA GEMM (product batch + final out GEMM).  64x128 tile.
//   GATHER_A   : A-rows gathered via idx (A indexed by node id)
//   DEG_VIA_IDX: A sequential/compact but deg looked up via idx[rloc]
// Row-major in/out (NOT blocked) — only the fused GEMM feeds the seg-sum.
// ---------------------------------------------------------------------------
template <bool GATHER_A, bool DEG_BIAS, bool DEG_VIA_IDX, bool OUT_BF16, bool PROD_BATCH>
__global__ __launch_bounds__(256) void mfma_gemm(
    const __bf16* __restrict__ A_in,
    const __bf16* __restrict__ Wt_in,
    const float* __restrict__ biasD,
    void* __restrict__ Cout_in,
    const int* __restrict__ idx,
    const int* __restrict__ degv,
    int M)
{
    const __bf16* A  = A_in;
    const __bf16* Wt = Wt_in;
    void* Cout = Cout_in;
    if constexpr (PROD_BATCH) {
        const int z = blockIdx.z;
        A    = A_in  + (size_t)(3 * (1 + (z >> 1)) + (z & 1)) * WSZ;
        Wt   = Wt_in + (size_t)(z >> 1) * WSZ;
        Cout = (void*)((__bf16*)Cout_in + (size_t)z * WSZ);
    }

    __shared__ __bf16 As[64 * 32];
    __shared__ __bf16 Bs[128 * 32];
    __shared__ int s_idx[64];

    const int t    = threadIdx.x;
    const int lane = t & 63;
    const int wave = t >> 6;
    const int m0   = blockIdx.x * 64;
    const int n0   = blockIdx.y * 128;

    if constexpr (GATHER_A || DEG_VIA_IDX) {
        if (t < 64) s_idx[t] = idx[m0 + t];
        __syncthreads();
    }

    const int arow  = t >> 2;
    const int acol8 = (t & 3) * 8;
    int anode;
    if constexpr (GATHER_A) {
        anode = s_idx[arow];
    } else {
        const int rg = m0 + arow;
        anode = (rg < M) ? rg : (M - 1);
    }
    const __bf16* aptr = A + (size_t)anode * HIDDEN + acol8;

    const __bf16* bptr[2];
    #pragma unroll
    for (int r = 0; r < 2; ++r) {
        const int c = r * 256 + t;
        bptr[r] = Wt + (size_t)(n0 + (c >> 2)) * HIDDEN + (c & 3) * 8;
    }

    f32x4 acc[8];
    #pragma unroll
    for (int i = 0; i < 8; ++i) acc[i] = (f32x4){0.f, 0.f, 0.f, 0.f};

    const int wm   = wave * 16;
    const int fm   = lane & 15;
    const int quad = lane >> 4;

    for (int k0 = 0; k0 < HIDDEN; k0 += 32) {
        __syncthreads();
        load_lds16(aptr + k0, (void*)(As + (size_t)t * 8));
        #pragma unroll
        for (int r = 0; r < 2; ++r)
            load_lds16(bptr[r] + k0, (void*)(Bs + (size_t)(r * 256 + t) * 8));
        __syncthreads();

        const bf16x8 af = *(const bf16x8*)(As + (wm + fm) * 32 + quad * 8);
        bf16x8 bfr[8];
        #pragma unroll
        for (int nt = 0; nt < 8; ++nt)
            bfr[nt] = *(const bf16x8*)(Bs + (nt * 16 + fm) * 32 + quad * 8);

        #pragma unroll
        for (int nt = 0; nt < 8; ++nt)
            acc[nt] = __builtin_amdgcn_mfma_f32_16x16x32_bf16(
                af, bfr[nt], acc[nt], 0, 0, 0);
    }

    float bd[8];
    #pragma unroll
    for (int nt = 0; nt < 8; ++nt)
        bd[nt] = DEG_BIAS ? biasD[n0 + nt * 16 + fm] : 0.f;

    #pragma unroll
    for (int rg = 0; rg < 4; ++rg) {
        const int rloc = wm + quad * 4 + rg;
        const int orow = m0 + rloc;
        if (!PROD_BATCH && orow >= M) continue;
        int dnode = orow;
        if constexpr (GATHER_A || DEG_VIA_IDX) dnode = s_idx[rloc];
        float bscale = 0.f;
        if constexpr (DEG_BIAS)
            bscale = (float)degv[dnode];
        #pragma unroll
        for (int nt = 0; nt < 8; ++nt) {
            const int col = n0 + nt * 16 + fm;
            float v = acc[nt][rg];
            if constexpr (DEG_BIAS) v += bscale * bd[nt];
            if constexpr (OUT_BF16)
                ((__bf16*)Cout)[(size_t)orow * HIDDEN + col] = (__bf16)v;
            else
                ((float*)Cout)[(size_t)orow * HIDDEN + col] = v;
        }
    }
}

// ---------------------------------------------------------------------------
// Weight prep, 12 z-slices in ONE launch:
//  z 0..8 : T[z][n][k] = (bf16)W_z[k][n]   (transpose; z = layer*3 + which)
//  z 9..10: cw_nt[z-9] = (bf16)conv_w[z-9] (straight convert)
//  z 11   : qprod — blocks (x<4, y==0): q[x][n] = sum_k cb_l[k]*W[k][n]
// ---------------------------------------------------------------------------
__global__ __launch_bounds__(256) void wconv_kernel(
    const float* __restrict__ f0_w, const float* __restrict__ f1_w,
    const float* __restrict__ conv_w, const float* __restrict__ conv_b,
    __bf16* __restrict__ wt_all, __bf16* __restrict__ cw_nt,
    float* __restrict__ q)
{
    const int z = blockIdx.z;
    const int kx = blockIdx.x * 32, nx = blockIdx.y * 32;
    const int tx = threadIdx.x, ty = threadIdx.y;

    if (z < 9) {
        const int layer = z / 3, which = z % 3;
        const float* W = ((which == 0) ? f0_w : (which == 1) ? f1_w : conv_w)
                         + (size_t)layer * WSZ;
        __bf16* T = wt_all + (size_t)z * WSZ;

        __shared__ float tile[32][33];
        for (int i = ty; i < 32; i += 8)
            tile[i][tx] = W[(size_t)(kx + i) * HIDDEN + nx + tx];
        __syncthreads();
        for (int i = ty; i < 32; i += 8)
            T[(size_t)(nx + i) * HIDDEN + kx + tx] = (__bf16)tile[tx][i];
    } else if (z < 11) {
        const int layer = z - 9;
        const float* W = conv_w + (size_t)layer * WSZ;
        __bf16* T = cw_nt + (size_t)layer * WSZ;
        for (int i = ty; i < 32; i += 8)
            T[(size_t)(kx + i) * HIDDEN + nx + tx] =
                (__bf16)W[(size_t)(kx + i) * HIDDEN + nx + tx];
    } else {
        // qprod: 4 active blocks (x<4, y==0), 256 threads each
        if (blockIdx.x >= 4 || blockIdx.y != 0) return;
        const int zq = blockIdx.x;
        const int l = zq >> 1, branch = zq & 1;
        const float* cb = conv_b + (size_t)l * HIDDEN;
        const float* W  = (branch ? f1_w : f0_w) + (size_t)(l + 1) * WSZ;
        const int n = ty * 32 + tx;
        float s = 0.f;
        #pragma unroll 4
        for (int k = 0; k < HIDDEN; ++k)
            s += cb[k] * W[(size_t)k * HIDDEN + n];
        q[(size_t)zq * HIDDEN + n] = s;
    }
}

// ---------------------------------------------------------------------------
// CSR build: histogram (+labeled-row flags, + zero sentinel rows of x0b)
//  -> 2-level PADDED scan (segments rounded up to 8) -> fill (+sentinel pads)
// ---------------------------------------------------------------------------
__global__ __launch_bounds__(256) void hist_kernel(
    const int* __restrict__ dst, const int* __restrict__ pos,
    int* __restrict__ counts, int* __restrict__ flags,
    __bf16* __restrict__ x0b)
{
    int e = blockIdx.x * 256 + threadIdx.x;
    if (e < N_EDGES) atomicAdd(&counts[dst[e]], 1);
    if (e < N_LABEL) flags[pos[e]] = 1;   // benign dup writes
    if (blockIdx.x == 0) {
        // zero the sentinel row (node N_NODES) in each of the 8 slices
        const int sl = threadIdx.x >> 5, c = threadIdx.x & 31;
        x0b[(size_t)sl * SLICE_ELEMS + (size_t)N_NODES * 32 + c] = (__bf16)0.f;
    }
}

__device__ __forceinline__ int block_incl_scan(int v, int* s, int t)
{
    s[t] = v; __syncthreads();
    #pragma unroll
    for (int off = 1; off < 256; off <<= 1) {
        int add = (t >= off) ? s[t - off] : 0;
        __syncthreads();
        s[t] += add;
        __syncthreads();
    }
    return s[t];
}

__global__ __launch_bounds__(256) void scan1_kernel(
    const int* __restrict__ counts, int* __restrict__ offs, int* __restrict__ bsum)
{
    __shared__ int s[256];
    const int t = threadIdx.x;
    const int i = blockIdx.x * 256 + t;
    const int pv = (counts[i] + 7) & ~7;       // padded segment length
    int incl = block_incl_scan(pv, s, t);
    offs[i] = incl - pv;
    if (t == 255) bsum[blockIdx.x] = incl;
}

__global__ __launch_bounds__(256) void scan2_kernel(
    const int* __restrict__ bsum, int* __restrict__ bbase)
{
    __shared__ int s[256];
    const int t = threadIdx.x;
    const int v = (t < SCAN_BLOCKS) ? bsum[t] : 0;
    int incl = block_incl_scan(v, s, t);
    bbase[t] = incl - v;
}

__global__ __launch_bounds__(256) void scan3_kernel(
    int* __restrict__ offs, const int* __restrict__ bbase,
    int* __restrict__ cursor, const int* __restrict__ counts,
    int* __restrict__ src_sorted)
{
    const int i = blockIdx.x * 256 + threadIdx.x;
    const int o = offs[i] + bbase[blockIdx.x];
    offs[i] = o;
    cursor[i] = o;
    // fill the padding tail of this segment with the zero-row sentinel
    const int v  = counts[i];
    const int pv = (v + 7) & ~7;
    for (int j = o + v; j < o + pv; ++j) src_sorted[j] = N_NODES;
}

__global__ __launch_bounds__(256) void fill_kernel(
    const int* __restrict__ src, const int* __restrict__ dst,
    int* __restrict__ cursor, int* __restrict__ src_sorted)
{
    int e = blockIdx.x * 256 + threadIdx.x;
    if (e < N_EDGES) {
        int p = atomicAdd(&cursor[dst[e]], 1);
        src_sorted[p] = src[e];
    }
}

// ---------------------------------------------------------------------------
// XCD-sliced pull-mode segment sum, R15: branch-free window-8.
// Segments are PADDED to a multiple of 8 with sentinel (zero-row) edges:
//   - indices loaded directly as aligned int4 pairs (no shfl broadcast)
//   - no per-element predication, no tail loop
//   - gathers via uniform base + 32-bit voffset (s-base addressing)
//   - accumulate as packed f32 pairs (v_pk_add_f32 path)
// slice = blockIdx.x & 7 pins each 3.2MB column slice to one XCD L2.
// ---------------------------------------------------------------------------
template <bool COMPACT>
__global__ __launch_bounds__(256) void seg_slice_kernel(
    const __bf16* __restrict__ x0b,
    const int* __restrict__ srcs,
    const int* __restrict__ offs,      // PADDED offsets (multiples of 8)
    const int* __restrict__ nodelist,
    __bf16* __restrict__ out)
{
    const int slice = blockIdx.x & 7;
    const int chunk = blockIdx.x >> 3;
    const int t    = threadIdx.x;
    const int wave = t >> 6;
    const int lane = t & 63;
    const int g    = lane >> 2;      // 16 groups per wave
    const int li   = lane & 3;       // 4 lanes per dst row, 8 cols each
    const int rw   = chunk * 64 + wave * 16 + g;
    if (!COMPACT && rw >= N_NODES) return;

    const int d    = COMPACT ? nodelist[rw] : rw;
    const int beg  = offs[d];
    const int pdeg = offs[d + 1] - beg;   // multiple of 8

    const char* xb = (const char*)(x0b + (size_t)slice * SLICE_ELEMS);
    const uint32_t lioff = (uint32_t)li * 16u;
    const int* sp = srcs + beg;           // 32B-aligned

    f32x2 a[4];
    #pragma unroll
    for (int j = 0; j < 4; ++j) a[j] = (f32x2){0.f, 0.f};

    int4 j0, j1;
    if (pdeg > 0) {
        j0 = *(const int4*)(sp);
        j1 = *(const int4*)(sp + 4);
    }

    for (int base = 0; base < pdeg; base += 8) {
        const int4 k0 = j0, k1 = j1;
        if (base + 8 < pdeg) {            // prefetch next window's indices
            j0 = *(const int4*)(sp + base + 8);
            j1 = *(const int4*)(sp + base + 12);
        }
        const uint4 c0 = *(const uint4*)(xb + (((uint32_t)k0.x << 6) + lioff));
        const uint4 c1 = *(const uint4*)(xb + (((uint32_t)k0.y << 6) + lioff));
        const uint4 c2 = *(const uint4*)(xb + (((uint32_t)k0.z << 6) + lioff));
        const uint4 c3 = *(const uint4*)(xb + (((uint32_t)k0.w << 6) + lioff));
        const uint4 c4 = *(const uint4*)(xb + (((uint32_t)k1.x << 6) + lioff));
        const uint4 c5 = *(const uint4*)(xb + (((uint32_t)k1.y << 6) + lioff));
        const uint4 c6 = *(const uint4*)(xb + (((uint32_t)k1.z << 6) + lioff));
        const uint4 c7 = *(const uint4*)(xb + (((uint32_t)k1.w << 6) + lioff));
        acc8(c0, a); acc8(c1, a); acc8(c2, a); acc8(c3, a);
        acc8(c4, a); acc8(c5, a); acc8(c6, a); acc8(c7, a);
    }

    bf16x8 o;
    #pragma unroll
    for (int j = 0; j < 4; ++j) {
        o[2 * j]     = (__bf16)a[j].x;
        o[2 * j + 1] = (__bf16)a[j].y;
    }
    *(bf16x8*)(out + (size_t)rw * HIDDEN + (slice << 5) + li * 8) = o;
}

extern "C" void kernel_launch(void* const* d_in, const int* in_sizes, int n_in,
                              void* d_out, int out_size, void* d_ws, size_t ws_size,
                              hipStream_t stream)
{
    const float* x       = (const float*)d_in[0];
    const float* f0_w    = (const float*)d_in[1];
    const float* f0_b    = (const float*)d_in[2];
    const float* f1_w    = (const float*)d_in[3];
    const float* f1_b    = (const float*)d_in[4];
    const float* conv_w  = (const float*)d_in[5];
    const float* conv_b  = (const float*)d_in[6];
    const int*   edge_src = (const int*)d_in[7];
    const int*   edge_dst = (const int*)d_in[8];
    const int*   pos      = (const int*)d_in[9];
    float* out = (float*)d_out;

    const size_t buf = (size_t)N_NODES * HIDDEN;   // 12.8M elems

    char* p = (char*)d_ws;
    __bf16* bufA   = (__bf16*)p; p += buf * 2;                 // 25.6 MB (row-major S)
    __bf16* bufB   = (__bf16*)p; p += SLICE_ELEMS * 8 * 2;     // 25.6 MB+ (blocked x0 + sentinel)
    __bf16* s_lbl  = (__bf16*)p; p += (size_t)N_LABEL * HIDDEN * 2;  // 4 MB
    __bf16* wt_all = (__bf16*)p; p += (size_t)9 * WSZ * 2;
    __bf16* prod   = (__bf16*)p; p += (size_t)4 * WSZ * 2;
    __bf16* cw_nt  = (__bf16*)p; p += (size_t)2 * WSZ * 2;
    float*  qv     = (float*)p;  p += (size_t)4 * HIDDEN * 4;
    int* counts     = (int*)p;  p += NPAD * 4;     // true degree (kept live!)
    int* flags      = (int*)p;  p += NPAD * 4;     // labeled-row bitmap
    int* offs       = (int*)p;  p += NPAD * 4;     // PADDED offsets
    int* cursor     = (int*)p;  p += NPAD * 4;
    int* bsum       = (int*)p;  p += 256 * 4;
    int* bbase      = (int*)p;  p += 256 * 4;
    int* src_sorted = (int*)p;  p += (size_t)(N_EDGES + 7 * NPAD) * 4;

    const int edge_blocks = (N_EDGES + 255) / 256;   // 3125

    // ---- CSR build + flags (one memset covers counts+flags) ----
    hipMemsetAsync(counts, 0, 2 * NPAD * sizeof(int), stream);
    hist_kernel<<<edge_blocks, 256, 0, stream>>>(edge_dst, pos, counts, flags, bufB);
    scan1_kernel<<<SCAN_BLOCKS, 256, 0, stream>>>(counts, offs, bsum);
    scan2_kernel<<<1, 256, 0, stream>>>(bsum, bbase);
    scan3_kernel<<<SCAN_BLOCKS, 256, 0, stream>>>(offs, bbase, cursor, counts, src_sorted);
    fill_kernel<<<edge_blocks, 256, 0, stream>>>(edge_src, edge_dst, cursor, src_sorted);

    // ---- weight prep: transpose (9) + straight Cw (2) + qprod, one launch ----
    wconv_kernel<<<dim3(8, 8, 12), dim3(32, 8), 0, stream>>>(
        f0_w, f1_w, conv_w, conv_b, wt_all, cw_nt, qv);

    // all 4 products prod_t[z] = (Cw_l · F_{l+1})^T in ONE batched launch
    mfma_gemm<false, false, false, true, true><<<dim3(4, 2, 4), 256, 0, stream>>>(
        wt_all, cw_nt, nullptr, prod, nullptr, nullptr, HIDDEN);

    const dim3 fused_grid(782, 2, 2);   // z=0 full (store-suppressed), z=1 label
    const dim3 lbl_grid(128, 2);

    __bf16* cur = bufA;              // S buffer (layer-0 GEMMs read x fp32)
    __bf16* tmp = bufB;              // x0 buffer, COLUMN-BLOCKED layout

    for (int l = 0; l < N_LAYERS; ++l) {
        const float* B0 = f0_b + (size_t)l * HIDDEN;
        const float* B1 = f1_b + (size_t)l * HIDDEN;

        if (l == 0) {
            // x0 = x@F0_0+b0 (all, minus labeled) ∪ x@F1_0+b1 (labeled)
            mfma_gemm_fused<false, true><<<fused_grid, 256, 0, stream>>>(
                x, wt_all + 0 * WSZ, wt_all + 1 * WSZ,
                nullptr, nullptr, B0, B1, tmp, pos, counts, flags, N_NODES);
        } else {
            // x0 = S@(Cw·F0_l)+deg*q0+b0 ∪ S@(Cw·F1_l)+deg*q1+b1 (folded conv)
            const int z0 = (l - 1) * 2;
            mfma_gemm_fused<true, false><<<fused_grid, 256, 0, stream>>>(
                cur, prod + (size_t)z0 * WSZ, prod + (size_t)(z0 + 1) * WSZ,
                qv + (size_t)z0 * HIDDEN, qv + (size_t)(z0 + 1) * HIDDEN,
                B0, B1, tmp, pos, counts, flags, N_NODES);
        }

        if (l < N_LAYERS - 1) {
            // S = segment_sum(x0[src]) at ALL nodes (tmp -> cur), XCD-sliced
            seg_slice_kernel<false><<<8 * SEG_CHUNKS, 256, 0, stream>>>(
                tmp, src_sorted, offs, nullptr, cur);
        } else {
            // S only at labeled dst nodes (tmp -> s_lbl, compact pos order)
            seg_slice_kernel<true><<<8 * (N_LABEL / 64), 256, 0, stream>>>(
                tmp, src_sorted, offs, pos, s_lbl);
            // out[i] = S_lbl[i] @ Cw_2 + deg[pos[i]]*cb_2  -> d_out (fp32)
            mfma_gemm<false, true, true, false, false><<<lbl_grid, 256, 0, stream>>>(
                s_lbl, wt_all + (size_t)(2 * 3 + 2) * WSZ,
                conv_b + (size_t)2 * HIDDEN, out, pos, counts, N_LABEL);
        }
    }
}